// Round 1
// baseline (350.920 us; speedup 1.0000x reference)
//
#include <hip/hip_runtime.h>

typedef float f32x4 __attribute__((ext_vector_type(4)));
typedef __bf16 bf16x8 __attribute__((ext_vector_type(8)));

#define DEV __device__ __forceinline__

constexpr int Bb = 32, Nn = 1024, Mm = 576, Dd = 768;
constexpr int QBLK = 64;
constexpr int NQT = Nn / QBLK;            // 16
constexpr int ST  = 192, NST = Mm / ST;   // 3 supertiles
constexpr int DCH = 64,  NDC = Dd / DCH;  // 12 d-chunks
constexpr int PVK = 32,  NPV = Mm / PVK;  // 18 kv tiles for PV

// LDS pitches (in ushorts)
constexpr int QP = 72;     // Q tile rows 64
constexpr int KP = 72;     // K tile rows 192
constexpr int PP = 584;    // P rows 64 (576 + 8 pad)
constexpr int VP = 40;     // Vt rows 768 (32 + 8 pad)

constexpr int QLOFF = 64 * QP;            // 4608
constexpr int KHOFF = QLOFF + 64 * QP;    // 9216
constexpr int KLOFF = KHOFF + 192 * KP;   // 23040
// total smA ushorts = 23040 + 13824 = 36864 (73728 B); Vt needs 768*40=30720 — fits.

constexpr float L2E = 1.44269504088896340736f;

DEV unsigned short f2bf(float f) {
  unsigned u = __builtin_bit_cast(unsigned, f);
  u += 0x7FFFu + ((u >> 16) & 1u);
  return (unsigned short)(u >> 16);
}
DEV float bf2f(unsigned short h) {
  return __builtin_bit_cast(float, ((unsigned)h) << 16);
}
DEV void cvt_hilo(float f, unsigned short &h, unsigned short &l) {
  h = f2bf(f);
  l = f2bf(f - bf2f(h));
}

__global__ __launch_bounds__(512, 2)
void ModalFusion_kernel(const float* __restrict__ Q, const float* __restrict__ KV,
                        float* __restrict__ Out)
{
  __shared__ unsigned short smA[36864];   // Q/K hi-lo staging; aliased as Vt in phase 3
  __shared__ unsigned short sP[64 * PP];  // P (bf16)
  __shared__ float sM[NST][64];           // per-supertile running max history
  __shared__ float sRa[4][64];            // cross-wave partial max
  __shared__ float sRb[4][64];            // cross-wave partial sum

  const int tid  = threadIdx.x;
  const int lane = tid & 63;
  const int w    = tid >> 6;    // wave 0..7
  const int g    = lane >> 4;   // 16-lane group 0..3
  const int ln   = lane & 15;

  // XCD-aware swizzle: keep all 16 q-tiles of a batch on one XCD
  int bid = blockIdx.x;
  int xcd = bid & 7, ii = bid >> 3;
  int b   = (xcd << 2) | (ii >> 4);
  int qt  = ii & 15;
  const int q0 = qt * QBLK;

  const float* Qb = Q  + ((size_t)b * Nn + q0) * Dd;
  const float* Kb = KV + (size_t)b * Mm * Dd;

  // ---------------- Phase 1: S = Q K^T (3-pass bf16) + online softmax ----------
  const int wq  = w >> 2;   // 0..1 : q rows [wq*32, +32)
  const int wkv = w & 3;    // 0..3 : kv cols [wkv*48, +48) within supertile
  const int koff = g << 3;

  float mrun[2][4], lrun[2][4];
#pragma unroll
  for (int mt = 0; mt < 2; ++mt)
#pragma unroll
    for (int i2 = 0; i2 < 4; ++i2) { mrun[mt][i2] = -INFINITY; lrun[mt][i2] = 0.0f; }

  const f32x4 vzero = {0.f, 0.f, 0.f, 0.f};

  for (int st = 0; st < NST; ++st) {
    f32x4 acc[2][3];
#pragma unroll
    for (int mt = 0; mt < 2; ++mt)
#pragma unroll
      for (int nt = 0; nt < 3; ++nt) acc[mt][nt] = vzero;

    for (int dc = 0; dc < NDC; ++dc) {
      __syncthreads();
      // stage Q chunk [64][64] f32 -> hi/lo bf16 (1024 float4, 2/thread)
#pragma unroll
      for (int r = 0; r < 2; ++r) {
        int idx = tid + (r << 9);
        int row = idx >> 4, c4 = idx & 15;
        f32x4 v = *(const f32x4*)(Qb + (size_t)row * Dd + dc * DCH + (c4 << 2));
        ushort4 uh, ul;
        cvt_hilo(v[0], uh.x, ul.x); cvt_hilo(v[1], uh.y, ul.y);
        cvt_hilo(v[2], uh.z, ul.z); cvt_hilo(v[3], uh.w, ul.w);
        *(ushort4*)&smA[row * QP + (c4 << 2)]         = uh;
        *(ushort4*)&smA[QLOFF + row * QP + (c4 << 2)] = ul;
      }
      // stage K chunk [192][64] f32 -> hi/lo (3072 float4, 6/thread)
#pragma unroll
      for (int r = 0; r < 6; ++r) {
        int idx = tid + (r << 9);
        int row = idx >> 4, c4 = idx & 15;
        f32x4 v = *(const f32x4*)(Kb + (size_t)(st * ST + row) * Dd + dc * DCH + (c4 << 2));
        ushort4 uh, ul;
        cvt_hilo(v[0], uh.x, ul.x); cvt_hilo(v[1], uh.y, ul.y);
        cvt_hilo(v[2], uh.z, ul.z); cvt_hilo(v[3], uh.w, ul.w);
        *(ushort4*)&smA[KHOFF + row * KP + (c4 << 2)] = uh;
        *(ushort4*)&smA[KLOFF + row * KP + (c4 << 2)] = ul;
      }
      __syncthreads();

      bf16x8 qh[2][2], ql[2][2];
#pragma unroll
      for (int mt = 0; mt < 2; ++mt)
#pragma unroll
        for (int ks = 0; ks < 2; ++ks) {
          int qr = (wq << 5) + (mt << 4) + ln;
          qh[mt][ks] = *(const bf16x8*)&smA[qr * QP + (ks << 5) + koff];
          ql[mt][ks] = *(const bf16x8*)&smA[QLOFF + qr * QP + (ks << 5) + koff];
        }
#pragma unroll
      for (int nt = 0; nt < 3; ++nt) {
        int kr = wkv * 48 + (nt << 4) + ln;
#pragma unroll
        for (int ks = 0; ks < 2; ++ks) {
          bf16x8 kh = *(const bf16x8*)&smA[KHOFF + kr * KP + (ks << 5) + koff];
          bf16x8 kl = *(const bf16x8*)&smA[KLOFF + kr * KP + (ks << 5) + koff];
#pragma unroll
          for (int mt = 0; mt < 2; ++mt) {
            acc[mt][nt] = __builtin_amdgcn_mfma_f32_16x16x32_bf16(qh[mt][ks], kh, acc[mt][nt], 0, 0, 0);
            acc[mt][nt] = __builtin_amdgcn_mfma_f32_16x16x32_bf16(ql[mt][ks], kh, acc[mt][nt], 0, 0, 0);
            acc[mt][nt] = __builtin_amdgcn_mfma_f32_16x16x32_bf16(qh[mt][ks], kl, acc[mt][nt], 0, 0, 0);
          }
        }
      }
    }

    // ---- online softmax update for this supertile ----
    float pm[2][4];
#pragma unroll
    for (int mt = 0; mt < 2; ++mt)
#pragma unroll
      for (int i2 = 0; i2 < 4; ++i2)
        pm[mt][i2] = fmaxf(fmaxf(acc[mt][0][i2], acc[mt][1][i2]), acc[mt][2][i2]);
#pragma unroll
    for (int mk = 1; mk < 16; mk <<= 1)
#pragma unroll
      for (int mt = 0; mt < 2; ++mt)
#pragma unroll
        for (int i2 = 0; i2 < 4; ++i2)
          pm[mt][i2] = fmaxf(pm[mt][i2], __shfl_xor(pm[mt][i2], mk, 64));
    if (ln == 0) {
#pragma unroll
      for (int mt = 0; mt < 2; ++mt)
#pragma unroll
        for (int i2 = 0; i2 < 4; ++i2)
          sRa[wkv][(wq << 5) + (mt << 4) + (g << 2) + i2] = pm[mt][i2];
    }
    __syncthreads();

    float mnew[2][4], ps[2][4];
#pragma unroll
    for (int mt = 0; mt < 2; ++mt)
#pragma unroll
      for (int i2 = 0; i2 < 4; ++i2) {
        int rw = (wq << 5) + (mt << 4) + (g << 2) + i2;
        float tmax = fmaxf(fmaxf(sRa[0][rw], sRa[1][rw]), fmaxf(sRa[2][rw], sRa[3][rw]));
        mnew[mt][i2] = fmaxf(mrun[mt][i2], tmax);
        ps[mt][i2] = 0.0f;
      }
#pragma unroll
    for (int mt = 0; mt < 2; ++mt)
#pragma unroll
      for (int nt = 0; nt < 3; ++nt)
#pragma unroll
        for (int i2 = 0; i2 < 4; ++i2) {
          float p = exp2f((acc[mt][nt][i2] - mnew[mt][i2]) * L2E);
          acc[mt][nt][i2] = p;
          ps[mt][i2] += p;
        }
#pragma unroll
    for (int mk = 1; mk < 16; mk <<= 1)
#pragma unroll
      for (int mt = 0; mt < 2; ++mt)
#pragma unroll
        for (int i2 = 0; i2 < 4; ++i2)
          ps[mt][i2] += __shfl_xor(ps[mt][i2], mk, 64);
    if (ln == 0) {
#pragma unroll
      for (int mt = 0; mt < 2; ++mt)
#pragma unroll
        for (int i2 = 0; i2 < 4; ++i2)
          sRb[wkv][(wq << 5) + (mt << 4) + (g << 2) + i2] = ps[mt][i2];
    }
    // write P (bf16, scaled by current supertile max)
#pragma unroll
    for (int mt = 0; mt < 2; ++mt)
#pragma unroll
      for (int nt = 0; nt < 3; ++nt)
#pragma unroll
        for (int i2 = 0; i2 < 4; ++i2) {
          int rw = (wq << 5) + (mt << 4) + (g << 2) + i2;
          sP[rw * PP + st * ST + wkv * 48 + (nt << 4) + ln] = f2bf(acc[mt][nt][i2]);
        }
    if (wkv == 0 && ln == 0) {
#pragma unroll
      for (int mt = 0; mt < 2; ++mt)
#pragma unroll
        for (int i2 = 0; i2 < 4; ++i2)
          sM[st][(wq << 5) + (mt << 4) + (g << 2) + i2] = mnew[mt][i2];
    }
    __syncthreads();
#pragma unroll
    for (int mt = 0; mt < 2; ++mt)
#pragma unroll
      for (int i2 = 0; i2 < 4; ++i2) {
        int rw = (wq << 5) + (mt << 4) + (g << 2) + i2;
        float ts = (sRb[0][rw] + sRb[1][rw]) + (sRb[2][rw] + sRb[3][rw]);
        float sc = exp2f((mrun[mt][i2] - mnew[mt][i2]) * L2E);
        lrun[mt][i2] = lrun[mt][i2] * sc + ts;
        mrun[mt][i2] = mnew[mt][i2];
      }
  }

  // ---- finalize per (supertile,row) factors: exp(m_st - m_fin) / l ----
  __syncthreads();
  if (wkv == 0 && ln == 0) {
#pragma unroll
    for (int mt = 0; mt < 2; ++mt)
#pragma unroll
      for (int i2 = 0; i2 < 4; ++i2) {
        int rw = (wq << 5) + (mt << 4) + (g << 2) + i2;
        float inv = 1.0f / lrun[mt][i2];
        float mf  = mrun[mt][i2];
#pragma unroll
        for (int st = 0; st < NST; ++st)
          sM[st][rw] = exp2f((sM[st][rw] - mf) * L2E) * inv;
      }
  }
  __syncthreads();

  // ---- rescale P in LDS ----
  {
    int row = tid >> 3, seg = tid & 7;
    unsigned* rp = (unsigned*)&sP[row * PP];
    float f0 = sM[0][row], f1 = sM[1][row], f2 = sM[2][row];
#pragma unroll 4
    for (int c = 0; c < 36; ++c) {
      int u_idx = seg * 36 + c;
      int kv = u_idx * 2;
      float f = (kv < 192) ? f0 : (kv < 384 ? f1 : f2);
      unsigned u = rp[u_idx];
      float a0 = bf2f((unsigned short)(u & 0xffff)) * f;
      float a1 = bf2f((unsigned short)(u >> 16)) * f;
      rp[u_idx] = (unsigned)f2bf(a0) | ((unsigned)f2bf(a1) << 16);
    }
  }
  __syncthreads();

  // ---------------- Phase 3: Out = P V  (V staged transposed, kv tiles of 32) ----
  f32x4 oacc[4][6];
#pragma unroll
  for (int mt = 0; mt < 4; ++mt)
#pragma unroll
    for (int nt = 0; nt < 6; ++nt) oacc[mt][nt] = vzero;

  for (int kt = 0; kt < NPV; ++kt) {
    __syncthreads();
    // stage Vt[d][kv]: V rows [kt*32,+32), all 768 d
#pragma unroll
    for (int p3 = 0; p3 < 3; ++p3) {
      int drow = (p3 << 8) + (tid >> 1);
      int kvh  = tid & 1;
      const float* src = Kb + (size_t)((kt << 5) + (kvh << 4)) * Dd + drow;
#pragma unroll
      for (int qd = 0; qd < 4; ++qd) {
        ushort4 u;
        u.x = f2bf(src[(size_t)(qd * 4 + 0) * Dd]);
        u.y = f2bf(src[(size_t)(qd * 4 + 1) * Dd]);
        u.z = f2bf(src[(size_t)(qd * 4 + 2) * Dd]);
        u.w = f2bf(src[(size_t)(qd * 4 + 3) * Dd]);
        *(ushort4*)&smA[drow * VP + (kvh << 4) + (qd << 2)] = u;
      }
    }
    __syncthreads();

    bf16x8 pa[4];
#pragma unroll
    for (int mt = 0; mt < 4; ++mt)
      pa[mt] = *(const bf16x8*)&sP[((mt << 4) + ln) * PP + (kt << 5) + koff];
#pragma unroll
    for (int nt = 0; nt < 6; ++nt) {
      bf16x8 bv = *(const bf16x8*)&smA[(w * 96 + (nt << 4) + ln) * VP + koff];
#pragma unroll
      for (int mt = 0; mt < 4; ++mt)
        oacc[mt][nt] = __builtin_amdgcn_mfma_f32_16x16x32_bf16(pa[mt], bv, oacc[mt][nt], 0, 0, 0);
    }
  }

  // ---- store ----
  float* ob = Out + ((size_t)b * Nn + q0) * Dd;
#pragma unroll
  for (int mt = 0; mt < 4; ++mt)
#pragma unroll
    for (int nt = 0; nt < 6; ++nt)
#pragma unroll
      for (int i2 = 0; i2 < 4; ++i2)
        ob[(size_t)((mt << 4) + (g << 2) + i2) * Dd + w * 96 + (nt << 4) + ln] = oacc[mt][nt][i2];
}

extern "C" void kernel_launch(void* const* d_in, const int* in_sizes, int n_in,
                              void* d_out, int out_size, void* d_ws, size_t ws_size,
                              hipStream_t stream) {
  const float* Q  = (const float*)d_in[0];
  const float* KV = (const float*)d_in[1];
  float* Out = (float*)d_out;
  dim3 grid(Bb * NQT);   // 512
  dim3 block(512);
  ModalFusion_kernel<<<grid, block, 0, stream>>>(Q, KV, Out);
}

// Round 3
// 229.232 us; speedup vs baseline: 1.5309x; 1.5309x over previous
//
#include <hip/hip_runtime.h>

typedef float f32x4 __attribute__((ext_vector_type(4)));
typedef _Float16 h8 __attribute__((ext_vector_type(8)));
typedef unsigned short us8 __attribute__((ext_vector_type(8)));

#define DEV __device__ __forceinline__

constexpr int Bb = 32, Nn = 1024, Mm = 576, Dd = 768;
constexpr float L2E = 1.44269504088896340736f;

// ws layout (ushort elems):
//   Khc: [b][st3][dc12][192 rows][64 cols, 16B-units XOR-swizzled by row&7]  (f16)
//   Vf:  [b][kc18][dtile48][lane64][8]  fragment-major V^T (f16)
constexpr size_t KH_ELEMS = (size_t)Bb * Mm * Dd;  // 14,155,776

DEV unsigned short f2h(float x) {
  _Float16 h = (_Float16)x;
  return __builtin_bit_cast(unsigned short, h);
}
struct HL { unsigned short h, l; };
DEV HL cvt_hl(float x) {
  _Float16 hh = (_Float16)x;
  float hf = (float)hh;
  _Float16 ll = (_Float16)(x - hf);
  HL r;
  r.h = __builtin_bit_cast(unsigned short, hh);
  r.l = __builtin_bit_cast(unsigned short, ll);
  return r;
}
DEV void gll16(const void* g, void* l) {
  __builtin_amdgcn_global_load_lds(
      (const __attribute__((address_space(1))) void*)g,
      (__attribute__((address_space(3))) void*)l, 16, 0, 0);
}

// ---------------- pre-pass: K -> Khc (chunked+swizzled f16) and Vf (fragment-major f16)
__global__ __launch_bounds__(256)
void fusion_prep(const float* __restrict__ K, unsigned short* __restrict__ Khc,
                 unsigned short* __restrict__ Vf)
{
  const int tid = threadIdx.x;
  const int blk = blockIdx.x;
  const int b = blk / 9, mt = blk % 9;
  const int m0 = mt * 64;
  // Kh mapping
  const int r  = tid >> 2;
  const int cg = (tid & 3) << 4;
  const int m  = m0 + r;
  const int st = m / 192, rr = m % 192;
  const float* srcK = K + ((size_t)b * Mm + m) * Dd;
  // Vf mapping
  const int dtl = (tid >> 6) & 3;
  const int l   = tid & 63;
  const int lg  = l >> 4, lln = l & 15;

  for (int dt = 0; dt < 12; ++dt) {
    const int d0 = dt << 6;
    // --- Khc ---
    f32x4 v0 = *(const f32x4*)(srcK + d0 + cg);
    f32x4 v1 = *(const f32x4*)(srcK + d0 + cg + 4);
    f32x4 v2 = *(const f32x4*)(srcK + d0 + cg + 8);
    f32x4 v3 = *(const f32x4*)(srcK + d0 + cg + 12);
    us8 h0, h1;
    h0[0]=f2h(v0[0]); h0[1]=f2h(v0[1]); h0[2]=f2h(v0[2]); h0[3]=f2h(v0[3]);
    h0[4]=f2h(v1[0]); h0[5]=f2h(v1[1]); h0[6]=f2h(v1[2]); h0[7]=f2h(v1[3]);
    h1[0]=f2h(v2[0]); h1[1]=f2h(v2[1]); h1[2]=f2h(v2[2]); h1[3]=f2h(v2[3]);
    h1[4]=f2h(v3[0]); h1[5]=f2h(v3[1]); h1[6]=f2h(v3[2]); h1[7]=f2h(v3[3]);
    const size_t kb = (((size_t)(b * 3 + st) * 12 + dt) * 192 + rr) << 6;
    const int u0 = cg >> 3;
    *(us8*)&Khc[kb + (((u0    ) ^ (rr & 7)) << 3)] = h0;
    *(us8*)&Khc[kb + (((u0 + 1) ^ (rr & 7)) << 3)] = h1;
    // --- Vf --- (each thread: 2 frag-units; lane j-gather is 4x64B coalesced)
#pragma unroll
    for (int q = 0; q < 2; ++q) {
      const int kv0 = m0 + (q << 5) + (lg << 3);
      const int d = d0 + (dtl << 4) + lln;
      us8 o;
#pragma unroll
      for (int j = 0; j < 8; ++j)
        o[j] = f2h(K[((size_t)b * Mm + kv0 + j) * Dd + d]);
      const size_t dst = (((((size_t)b * 18 + (mt << 1) + q) * 48 + (dt << 2) + dtl) << 6) + l) << 3;
      *(us8*)&Vf[dst] = o;
    }
  }
}

// ---------------- main fused kernel
__global__ __launch_bounds__(512, 2)
void fusion_main(const float* __restrict__ Q, const unsigned short* __restrict__ Khc,
                 const unsigned short* __restrict__ Vf, float* __restrict__ Out)
{
  __shared__ unsigned short bufK[2][12288];   // [192][64] f16, swizzled
  __shared__ unsigned short bufQh[2][4096];   // [64][64] f16, swizzled
  __shared__ unsigned short bufQl[2][4096];
  __shared__ unsigned short sP[12288];        // [64][192] f16, swizzled
  __shared__ float sRa[4][64];
  __shared__ float sRb[4][64];

  const int tid  = threadIdx.x;
  const int lane = tid & 63;
  const int w    = tid >> 6;
  const int g    = lane >> 4;
  const int ln   = lane & 15;
  const int wq   = w >> 2;   // 0..1: q rows [wq*32,+32)
  const int wkv  = w & 3;    // QK: kv slice [wkv*48,+48)
  const int wd   = w & 3;    // PV: d slice [wd*192,+192)

  // XCD swizzle: each XCD round works on 2 batches -> K/V L2-resident
  const int bid = blockIdx.x;
  const int xcd = bid & 7, ii = bid >> 3;
  const int b  = (xcd << 2) | (ii >> 4);
  const int q0 = (ii & 15) * 64;

  const float* Qb = Q + ((size_t)b * Nn + q0) * Dd;
  const char* KhB = (const char*)Khc + (size_t)b * 36 * 24576;
  const unsigned short* VfB = Vf + (size_t)b * 18 * 48 * 512;

  // Q staging thread constants
  const int sqr = tid >> 3;               // row 0..63
  const int squ = tid & 7;                // 16B unit 0..7
  const int sqidx = sqr * 64 + ((squ ^ (sqr & 7)) << 3);
  const int sqc = squ << 3;

  f32x4 O[2][12];
#pragma unroll
  for (int mt = 0; mt < 2; ++mt)
#pragma unroll
    for (int nt = 0; nt < 12; ++nt) O[mt][nt] = (f32x4){0.f, 0.f, 0.f, 0.f};
  float mrun[2][4], lrun[2][4];
#pragma unroll
  for (int mt = 0; mt < 2; ++mt)
#pragma unroll
    for (int i2 = 0; i2 < 4; ++i2) { mrun[mt][i2] = -INFINITY; lrun[mt][i2] = 0.f; }

  // prologue: stage chunk (st0, dc0) into buf0
  {
#pragma unroll
    for (int j = 0; j < 3; ++j) {
      const int unit = w * 3 + j;
      gll16(KhB + unit * 1024 + (lane << 4), (void*)&bufK[0][unit * 512]);
    }
    f32x4 a = *(const f32x4*)(Qb + (size_t)sqr * Dd + sqc);
    f32x4 c = *(const f32x4*)(Qb + (size_t)sqr * Dd + sqc + 4);
    us8 hv, lv;
#pragma unroll
    for (int k = 0; k < 4; ++k) {
      HL r0 = cvt_hl(a[k] * L2E), r1 = cvt_hl(c[k] * L2E);
      hv[k] = r0.h; lv[k] = r0.l; hv[k+4] = r1.h; lv[k+4] = r1.l;
    }
    *(us8*)&bufQh[0][sqidx] = hv;
    *(us8*)&bufQl[0][sqidx] = lv;
    __syncthreads();
  }

  for (int st = 0; st < 3; ++st) {
    f32x4 acc[2][3];
#pragma unroll
    for (int mt = 0; mt < 2; ++mt)
#pragma unroll
      for (int nt = 0; nt < 3; ++nt) acc[mt][nt] = (f32x4){0.f, 0.f, 0.f, 0.f};

    for (int dc = 0; dc < 12; ++dc) {
      const int cur = dc & 1, nxt = cur ^ 1;
      const bool do_stage = !(st == 2 && dc == 11);
      const int nst = (dc == 11) ? st + 1 : st;
      const int ndc = (dc == 11) ? 0 : dc + 1;
      f32x4 qa, qc;
      if (do_stage) {  // issue next-chunk loads early (hide under MFMA)
        const char* src = KhB + ((size_t)(nst * 12 + ndc)) * 24576;
#pragma unroll
        for (int j = 0; j < 3; ++j) {
          const int unit = w * 3 + j;
          gll16(src + unit * 1024 + (lane << 4), (void*)&bufK[nxt][unit * 512]);
        }
        const float* qs = Qb + (size_t)sqr * Dd + ndc * 64 + sqc;
        qa = *(const f32x4*)qs;
        qc = *(const f32x4*)(qs + 4);
      }
      // compute on cur
      h8 qh[2][2], ql[2][2];
#pragma unroll
      for (int mt = 0; mt < 2; ++mt)
#pragma unroll
        for (int ks = 0; ks < 2; ++ks) {
          const int qr = (wq << 5) + (mt << 4) + ln;
          const int idx = qr * 64 + ((((ks << 2) + g) ^ (qr & 7)) << 3);
          qh[mt][ks] = *(const h8*)&bufQh[cur][idx];
          ql[mt][ks] = *(const h8*)&bufQl[cur][idx];
        }
#pragma unroll
      for (int nt = 0; nt < 3; ++nt) {
        const int kr = wkv * 48 + (nt << 4) + ln;
#pragma unroll
        for (int ks = 0; ks < 2; ++ks) {
          const h8 kf = *(const h8*)&bufK[cur][kr * 64 + ((((ks << 2) + g) ^ (kr & 7)) << 3)];
#pragma unroll
          for (int mt = 0; mt < 2; ++mt) {
            acc[mt][nt] = __builtin_amdgcn_mfma_f32_16x16x32_f16(qh[mt][ks], kf, acc[mt][nt], 0, 0, 0);
            acc[mt][nt] = __builtin_amdgcn_mfma_f32_16x16x32_f16(ql[mt][ks], kf, acc[mt][nt], 0, 0, 0);
          }
        }
      }
      if (do_stage) {  // convert+write Q late (loads landed under MFMA)
        us8 hv, lv;
#pragma unroll
        for (int k = 0; k < 4; ++k) {
          HL r0 = cvt_hl(qa[k] * L2E), r1 = cvt_hl(qc[k] * L2E);
          hv[k] = r0.h; lv[k] = r0.l; hv[k+4] = r1.h; lv[k+4] = r1.l;
        }
        *(us8*)&bufQh[nxt][sqidx] = hv;
        *(us8*)&bufQl[nxt][sqidx] = lv;
      }
      __syncthreads();
    }

    // ---- online softmax (exp2 domain; Q pre-scaled by log2(e)) ----
    float pm[2][4];
#pragma unroll
    for (int mt = 0; mt < 2; ++mt)
#pragma unroll
      for (int i2 = 0; i2 < 4; ++i2)
        pm[mt][i2] = fmaxf(fmaxf(acc[mt][0][i2], acc[mt][1][i2]), acc[mt][2][i2]);
#pragma unroll
    for (int mk = 1; mk < 16; mk <<= 1)
#pragma unroll
      for (int mt = 0; mt < 2; ++mt)
#pragma unroll
        for (int i2 = 0; i2 < 4; ++i2)
          pm[mt][i2] = fmaxf(pm[mt][i2], __shfl_xor(pm[mt][i2], mk, 64));
    if (ln == 0) {
#pragma unroll
      for (int mt = 0; mt < 2; ++mt)
#pragma unroll
        for (int i2 = 0; i2 < 4; ++i2)
          sRa[wkv][(wq << 5) + (mt << 4) + (g << 2) + i2] = pm[mt][i2];
    }
    __syncthreads();

    float mnew[2][4], ps[2][4];
#pragma unroll
    for (int mt = 0; mt < 2; ++mt)
#pragma unroll
      for (int i2 = 0; i2 < 4; ++i2) {
        const int rw = (wq << 5) + (mt << 4) + (g << 2) + i2;
        const float t = fmaxf(fmaxf(sRa[0][rw], sRa[1][rw]), fmaxf(sRa[2][rw], sRa[3][rw]));
        mnew[mt][i2] = fmaxf(mrun[mt][i2], t);
        ps[mt][i2] = 0.f;
      }
#pragma unroll
    for (int mt = 0; mt < 2; ++mt)
#pragma unroll
      for (int nt = 0; nt < 3; ++nt)
#pragma unroll
        for (int i2 = 0; i2 < 4; ++i2) {
          const float p = exp2f(acc[mt][nt][i2] - mnew[mt][i2]);
          acc[mt][nt][i2] = p;
          ps[mt][i2] += p;
        }
#pragma unroll
    for (int mk = 1; mk < 16; mk <<= 1)
#pragma unroll
      for (int mt = 0; mt < 2; ++mt)
#pragma unroll
        for (int i2 = 0; i2 < 4; ++i2)
          ps[mt][i2] += __shfl_xor(ps[mt][i2], mk, 64);
    if (ln == 0) {
#pragma unroll
      for (int mt = 0; mt < 2; ++mt)
#pragma unroll
        for (int i2 = 0; i2 < 4; ++i2)
          sRb[wkv][(wq << 5) + (mt << 4) + (g << 2) + i2] = ps[mt][i2];
    }
    // write P (f16, unnormalized) into swizzled sP
#pragma unroll
    for (int mt = 0; mt < 2; ++mt)
#pragma unroll
      for (int nt = 0; nt < 3; ++nt)
#pragma unroll
        for (int i2 = 0; i2 < 4; ++i2) {
          const int rw = (wq << 5) + (mt << 4) + (g << 2) + i2;
          const int u = wkv * 6 + (nt << 1) + (ln >> 3);
          sP[rw * 192 + ((u ^ (rw & 7)) << 3) + (ln & 7)] = f2h(acc[mt][nt][i2]);
        }
    // rescale O by exp2(m_old - m_new)
    float sc[2][4];
#pragma unroll
    for (int mt = 0; mt < 2; ++mt)
#pragma unroll
      for (int i2 = 0; i2 < 4; ++i2) sc[mt][i2] = exp2f(mrun[mt][i2] - mnew[mt][i2]);
#pragma unroll
    for (int mt = 0; mt < 2; ++mt)
#pragma unroll
      for (int nt = 0; nt < 12; ++nt)
#pragma unroll
        for (int i2 = 0; i2 < 4; ++i2) O[mt][nt][i2] *= sc[mt][i2];
    __syncthreads();
#pragma unroll
    for (int mt = 0; mt < 2; ++mt)
#pragma unroll
      for (int i2 = 0; i2 < 4; ++i2) {
        const int rw = (wq << 5) + (mt << 4) + (g << 2) + i2;
        const float ts = (sRb[0][rw] + sRb[1][rw]) + (sRb[2][rw] + sRb[3][rw]);
        lrun[mt][i2] = lrun[mt][i2] * sc[mt][i2] + ts;
        mrun[mt][i2] = mnew[mt][i2];
      }

    // ---- PV: O += P * V  (V frags direct from global, no barriers) ----
#pragma unroll 1
    for (int kc = 0; kc < 6; ++kc) {
      const int kcg = st * 6 + kc;
      h8 pa[2];
#pragma unroll
      for (int mt = 0; mt < 2; ++mt) {
        const int row = (wq << 5) + (mt << 4) + ln;
        pa[mt] = *(const h8*)&sP[row * 192 + ((((kc << 2) + g) ^ (row & 7)) << 3)];
      }
      const unsigned short* vb = VfB + (((size_t)kcg * 48 + wd * 12) << 9) + (lane << 3);
#pragma unroll
      for (int nt = 0; nt < 12; ++nt) {
        const h8 vf = *(const h8*)(vb + (nt << 9));
#pragma unroll
        for (int mt = 0; mt < 2; ++mt)
          O[mt][nt] = __builtin_amdgcn_mfma_f32_16x16x32_f16(pa[mt], vf, O[mt][nt], 0, 0, 0);
      }
    }
  }

  // ---- normalize + store ----
  float inv[2][4];
#pragma unroll
  for (int mt = 0; mt < 2; ++mt)
#pragma unroll
    for (int i2 = 0; i2 < 4; ++i2) inv[mt][i2] = 1.0f / lrun[mt][i2];
  float* ob = Out + ((size_t)b * Nn + q0) * Dd;
#pragma unroll
  for (int mt = 0; mt < 2; ++mt)
#pragma unroll
    for (int nt = 0; nt < 12; ++nt)
#pragma unroll
      for (int i2 = 0; i2 < 4; ++i2) {
        const int row = (wq << 5) + (mt << 4) + (g << 2) + i2;
        const int col = wd * 192 + (nt << 4) + ln;
        ob[(size_t)row * Dd + col] = O[mt][nt][i2] * inv[mt][i2];
      }
}

extern "C" void kernel_launch(void* const* d_in, const int* in_sizes, int n_in,
                              void* d_out, int out_size, void* d_ws, size_t ws_size,
                              hipStream_t stream) {
  const float* Q = (const float*)d_in[0];
  const float* K = (const float*)d_in[1];
  float* Out = (float*)d_out;
  unsigned short* Khc = (unsigned short*)d_ws;
  unsigned short* Vf = Khc + KH_ELEMS;
  fusion_prep<<<dim3(Bb * 9), dim3(256), 0, stream>>>(K, Khc, Vf);
  fusion_main<<<dim3(Bb * 16), dim3(512), 0, stream>>>(Q, Khc, Vf, Out);
}

// Round 4
// 218.304 us; speedup vs baseline: 1.6075x; 1.0501x over previous
//
#include <hip/hip_runtime.h>

typedef float f32x4 __attribute__((ext_vector_type(4)));
typedef _Float16 h8 __attribute__((ext_vector_type(8)));
typedef unsigned short us8 __attribute__((ext_vector_type(8)));

#define DEV __device__ __forceinline__

constexpr int Bb = 32, Nn = 1024, Mm = 576, Dd = 768;
constexpr float L2E = 1.44269504088896340736f;

// ws layout (ushort elems), both fragment-major for 16x16x32 f16 MFMA:
//   Kf: [b][kvtile 36][dc 24][lane 64][8]   B-frag: K[kvt*16+(l&15)][dc*32+(l>>4)*8+j]
//   Vf: [b][kc 18][dtile 48][lane 64][8]    B-frag: V[kc*32+(l>>4)*8+j][dt*16+(l&15)]
constexpr size_t KF_ELEMS = (size_t)Bb * 36 * 24 * 512;  // 14,155,776

DEV unsigned short f2h(float x) {
  _Float16 h = (_Float16)x;
  return __builtin_bit_cast(unsigned short, h);
}

// ---------------- pre-pass: K -> Kf, Vf (fragment-major f16)
__global__ __launch_bounds__(256)
void fusion_prep(const float* __restrict__ K, unsigned short* __restrict__ Kf,
                 unsigned short* __restrict__ Vf)
{
  const int t = threadIdx.x;
  const int b = blockIdx.x / 24, dc = blockIdx.x % 24;
  const int l = t & 63;
  // --- Kf: 9 iters cover 36 kvtiles ---
  {
    const int lt = t >> 6;               // 0..3
    const int ro = l & 15, go = l >> 4;
#pragma unroll
    for (int it = 0; it < 9; ++it) {
      const int kvt = it * 4 + lt;
      const float* src = K + ((size_t)(b * Mm + kvt * 16 + ro)) * Dd + dc * 32 + go * 8;
      f32x4 v0 = *(const f32x4*)src;
      f32x4 v1 = *(const f32x4*)(src + 4);
      us8 h;
      h[0]=f2h(v0[0]); h[1]=f2h(v0[1]); h[2]=f2h(v0[2]); h[3]=f2h(v0[3]);
      h[4]=f2h(v1[0]); h[5]=f2h(v1[1]); h[6]=f2h(v1[2]); h[7]=f2h(v1[3]);
      *(us8*)&Kf[(((size_t)((b * 36 + kvt) * 24 + dc)) << 9) + l * 8] = h;
    }
  }
  // --- Vf: 9 iters cover 18 kc x 2 dtl ---
  {
    const int kch = t >> 7;              // 0..1
    const int dtl = (t >> 6) & 1;        // 0..1
    const int d = dc * 32 + dtl * 16 + (l & 15);
    const int kvo = (l >> 4) * 8;
#pragma unroll
    for (int it = 0; it < 9; ++it) {
      const int kc = it * 2 + kch;
      const int kv0 = kc * 32 + kvo;
      us8 o;
#pragma unroll
      for (int j = 0; j < 8; ++j)
        o[j] = f2h(K[((size_t)(b * Mm + kv0 + j)) * Dd + d]);
      *(us8*)&Vf[(((size_t)((b * 18 + kc) * 48 + dc * 2 + dtl)) << 9) + l * 8] = o;
    }
  }
}

// ---------------- main fused kernel: barrier-free QK, one-shot softmax, direct-frag PV
__global__ __launch_bounds__(512, 4)
void fusion_main(const float* __restrict__ Q, const unsigned short* __restrict__ Kf,
                 const unsigned short* __restrict__ Vf, float* __restrict__ Out)
{
  __shared__ unsigned short sP[64 * 576];   // normalized P, f16, XOR-swizzled (72 KB)
  __shared__ float sRa[4][64];
  __shared__ float sRb[4][64];

  const int tid  = threadIdx.x;
  const int lane = tid & 63;
  const int w    = tid >> 6;
  const int g    = lane >> 4;
  const int ln   = lane & 15;
  const int wq   = w >> 2;   // 0..1: q rows [wq*32,+32)
  const int wkv  = w & 3;    // QK: kv slice [wkv*144,+144)
  const int wd   = w & 3;    // PV: d slice [wd*192,+192)

  // XCD swizzle
  const int bid = blockIdx.x;
  const int xcd = bid & 7, ii = bid >> 3;
  const int b  = (xcd << 2) | (ii >> 4);
  const int q0 = (ii & 15) * 64;

  const float* Qw = Q + ((size_t)(b * Nn + q0 + wq * 32)) * Dd;
  const unsigned short* KfW = Kf + (((size_t)(b * 36 + wkv * 9)) * 24 << 9);
  const unsigned short* VfB = Vf + ((size_t)b * 18 * 48 << 9);

  // ---------------- QK: acc[mt 2][nt 9] covers [32 q][144 kv], full K-dim sweep, NO barriers
  f32x4 acc[2][9];
#pragma unroll
  for (int mt = 0; mt < 2; ++mt)
#pragma unroll
    for (int nt = 0; nt < 9; ++nt) acc[mt][nt] = (f32x4){0.f, 0.f, 0.f, 0.f};

#pragma unroll 1
  for (int dc = 0; dc < 24; ++dc) {
    h8 qh[2], ql[2];
#pragma unroll
    for (int mt = 0; mt < 2; ++mt) {
      const float* qs = Qw + (size_t)(mt * 16 + ln) * Dd + dc * 32 + g * 8;
      f32x4 a = *(const f32x4*)qs;
      f32x4 c = *(const f32x4*)(qs + 4);
#pragma unroll
      for (int k2 = 0; k2 < 4; ++k2) {
        float x = a[k2] * L2E;
        _Float16 hh = (_Float16)x;
        qh[mt][k2] = hh;
        ql[mt][k2] = (_Float16)(x - (float)hh);
        float y = c[k2] * L2E;
        _Float16 hh2 = (_Float16)y;
        qh[mt][k2 + 4] = hh2;
        ql[mt][k2 + 4] = (_Float16)(y - (float)hh2);
      }
    }
#pragma unroll
    for (int nt = 0; nt < 9; ++nt) {
      const h8 kf = *(const h8*)&KfW[(((size_t)(nt * 24 + dc)) << 9) + lane * 8];
#pragma unroll
      for (int mt = 0; mt < 2; ++mt) {
        acc[mt][nt] = __builtin_amdgcn_mfma_f32_16x16x32_f16(qh[mt], kf, acc[mt][nt], 0, 0, 0);
        acc[mt][nt] = __builtin_amdgcn_mfma_f32_16x16x32_f16(ql[mt], kf, acc[mt][nt], 0, 0, 0);
      }
    }
  }

  // ---------------- one-shot softmax (exp2 domain; Q pre-scaled by log2 e)
  float pm[2][4];
#pragma unroll
  for (int mt = 0; mt < 2; ++mt)
#pragma unroll
    for (int i2 = 0; i2 < 4; ++i2) {
      float v = acc[mt][0][i2];
#pragma unroll
      for (int nt = 1; nt < 9; ++nt) v = fmaxf(v, acc[mt][nt][i2]);
      pm[mt][i2] = v;
    }
#pragma unroll
  for (int mk = 1; mk < 16; mk <<= 1)
#pragma unroll
    for (int mt = 0; mt < 2; ++mt)
#pragma unroll
      for (int i2 = 0; i2 < 4; ++i2)
        pm[mt][i2] = fmaxf(pm[mt][i2], __shfl_xor(pm[mt][i2], mk, 64));
  if (ln == 0) {
#pragma unroll
    for (int mt = 0; mt < 2; ++mt)
#pragma unroll
      for (int i2 = 0; i2 < 4; ++i2)
        sRa[wkv][(wq << 5) + (mt << 4) + (g << 2) + i2] = pm[mt][i2];
  }
  __syncthreads();

  float mfin[2][4], ps[2][4];
#pragma unroll
  for (int mt = 0; mt < 2; ++mt)
#pragma unroll
    for (int i2 = 0; i2 < 4; ++i2) {
      const int rw = (wq << 5) + (mt << 4) + (g << 2) + i2;
      mfin[mt][i2] = fmaxf(fmaxf(sRa[0][rw], sRa[1][rw]), fmaxf(sRa[2][rw], sRa[3][rw]));
      ps[mt][i2] = 0.f;
    }
#pragma unroll
  for (int mt = 0; mt < 2; ++mt)
#pragma unroll
    for (int nt = 0; nt < 9; ++nt)
#pragma unroll
      for (int i2 = 0; i2 < 4; ++i2) {
        const float p = exp2f(acc[mt][nt][i2] - mfin[mt][i2]);
        acc[mt][nt][i2] = p;
        ps[mt][i2] += p;
      }
#pragma unroll
  for (int mk = 1; mk < 16; mk <<= 1)
#pragma unroll
    for (int mt = 0; mt < 2; ++mt)
#pragma unroll
      for (int i2 = 0; i2 < 4; ++i2)
        ps[mt][i2] += __shfl_xor(ps[mt][i2], mk, 64);
  if (ln == 0) {
#pragma unroll
    for (int mt = 0; mt < 2; ++mt)
#pragma unroll
      for (int i2 = 0; i2 < 4; ++i2)
        sRb[wkv][(wq << 5) + (mt << 4) + (g << 2) + i2] = ps[mt][i2];
  }
  __syncthreads();

  // normalize P and write to swizzled sP
#pragma unroll
  for (int mt = 0; mt < 2; ++mt)
#pragma unroll
    for (int i2 = 0; i2 < 4; ++i2) {
      const int rw = (wq << 5) + (mt << 4) + (g << 2) + i2;
      const float inv = 1.0f / ((sRb[0][rw] + sRb[1][rw]) + (sRb[2][rw] + sRb[3][rw]));
#pragma unroll
      for (int nt = 0; nt < 9; ++nt) {
        const int u = wkv * 18 + (nt << 1) + (ln >> 3);   // 16B unit of col
        sP[rw * 576 + ((u ^ (rw & 7)) << 3) + (ln & 7)] = f2h(acc[mt][nt][i2] * inv);
      }
    }
  __syncthreads();

  // ---------------- PV: O = P * V  (P from LDS, V frags direct from global)
  f32x4 O[2][12];
#pragma unroll
  for (int mt = 0; mt < 2; ++mt)
#pragma unroll
    for (int nt = 0; nt < 12; ++nt) O[mt][nt] = (f32x4){0.f, 0.f, 0.f, 0.f};

#pragma unroll 1
  for (int kc = 0; kc < 18; ++kc) {
    h8 pa[2];
#pragma unroll
    for (int mt = 0; mt < 2; ++mt) {
      const int row = (wq << 5) + (mt << 4) + ln;
      const int u = (kc << 2) + g;
      pa[mt] = *(const h8*)&sP[row * 576 + ((u ^ (row & 7)) << 3)];
    }
    const unsigned short* vb = VfB + (((size_t)(kc * 48 + wd * 12)) << 9) + lane * 8;
#pragma unroll
    for (int nt = 0; nt < 12; ++nt) {
      const h8 vf = *(const h8*)(vb + ((size_t)nt << 9));
#pragma unroll
      for (int mt = 0; mt < 2; ++mt)
        O[mt][nt] = __builtin_amdgcn_mfma_f32_16x16x32_f16(pa[mt], vf, O[mt][nt], 0, 0, 0);
    }
  }

  // ---------------- store (already normalized)
  float* ob = Out + ((size_t)(b * Nn + q0 + wq * 32)) * Dd;
#pragma unroll
  for (int mt = 0; mt < 2; ++mt)
#pragma unroll
    for (int nt = 0; nt < 12; ++nt)
#pragma unroll
      for (int i2 = 0; i2 < 4; ++i2) {
        const int row = (mt << 4) + (g << 2) + i2;
        const int col = wd * 192 + (nt << 4) + ln;
        ob[(size_t)row * Dd + col] = O[mt][nt][i2];
      }
}

extern "C" void kernel_launch(void* const* d_in, const int* in_sizes, int n_in,
                              void* d_out, int out_size, void* d_ws, size_t ws_size,
                              hipStream_t stream) {
  const float* Q = (const float*)d_in[0];
  const float* K = (const float*)d_in[1];
  float* Out = (float*)d_out;
  unsigned short* Kf = (unsigned short*)d_ws;
  unsigned short* Vf = Kf + KF_ELEMS;
  fusion_prep<<<dim3(Bb * 24), dim3(256), 0, stream>>>(K, Kf, Vf);
  fusion_main<<<dim3(Bb * 16), dim3(512), 0, stream>>>(Q, Kf, Vf, Out);
}

// Round 5
// 143.426 us; speedup vs baseline: 2.4467x; 1.5221x over previous
//
#include <hip/hip_runtime.h>

typedef float f32x4 __attribute__((ext_vector_type(4)));
typedef _Float16 h8 __attribute__((ext_vector_type(8)));
typedef unsigned short us8 __attribute__((ext_vector_type(8)));
typedef unsigned short us4 __attribute__((ext_vector_type(4)));

#define DEV __device__ __forceinline__

constexpr int Bb = 32, Nn = 1024, Mm = 576, Dd = 768;
constexpr float L2E = 1.44269504088896340736f;

// ws layout (ushort elems), fragment-major for 16x16x32 f16 MFMA:
//   Kf: [b][kvtile 36][dc 24][lane 64][8]   B-frag: K[kvt*16+(l&15)][dc*32+(l>>4)*8+j]
//   Vf: [b][kc 18][dtile 48][lane 64][8]    B-frag: V[kc*32+(l>>4)*8+j][dt*16+(l&15)]
constexpr size_t KF_ELEMS = (size_t)Bb * 36 * 24 * 512;  // 14,155,776

DEV unsigned short f2h(float x) {
  _Float16 h = (_Float16)x;
  return __builtin_bit_cast(unsigned short, h);
}
DEV void gll16(const void* g, void* l) {
  __builtin_amdgcn_global_load_lds(
      (const __attribute__((address_space(1))) void*)g,
      (__attribute__((address_space(3))) void*)l, 16, 0, 0);
}

// ---------------- pre-pass: K -> Kf, Vf (fragment-major f16)
__global__ __launch_bounds__(256)
void fusion_prep(const float* __restrict__ K, unsigned short* __restrict__ Kf,
                 unsigned short* __restrict__ Vf)
{
  const int t = threadIdx.x;
  const int b = blockIdx.x / 24, dc = blockIdx.x % 24;
  const int l = t & 63;
  // --- Kf ---
  {
    const int lt = t >> 6;
    const int ro = l & 15, go = l >> 4;
#pragma unroll
    for (int it = 0; it < 9; ++it) {
      const int kvt = it * 4 + lt;
      const float* src = K + ((size_t)(b * Mm + kvt * 16 + ro)) * Dd + dc * 32 + go * 8;
      f32x4 v0 = *(const f32x4*)src;
      f32x4 v1 = *(const f32x4*)(src + 4);
      us8 h;
      h[0]=f2h(v0[0]); h[1]=f2h(v0[1]); h[2]=f2h(v0[2]); h[3]=f2h(v0[3]);
      h[4]=f2h(v1[0]); h[5]=f2h(v1[1]); h[6]=f2h(v1[2]); h[7]=f2h(v1[3]);
      *(us8*)&Kf[(((size_t)((b * 36 + kvt) * 24 + dc)) << 9) + l * 8] = h;
    }
  }
  // --- Vf ---
  {
    const int kch = t >> 7;
    const int dtl = (t >> 6) & 1;
    const int d = dc * 32 + dtl * 16 + (l & 15);
    const int kvo = (l >> 4) * 8;
#pragma unroll
    for (int it = 0; it < 9; ++it) {
      const int kc = it * 2 + kch;
      const int kv0 = kc * 32 + kvo;
      us8 o;
#pragma unroll
      for (int j = 0; j < 8; ++j)
        o[j] = f2h(K[((size_t)(b * Mm + kv0 + j)) * Dd + d]);
      *(us8*)&Vf[(((size_t)((b * 18 + kc) * 48 + dc * 2 + dtl)) << 9) + l * 8] = o;
    }
  }
}

// ---------------- main: LDS-staged pipelined QK + one-shot softmax + 2-pass PV
// LDS map (bytes): bufK[2] @ 0 / 36864 (36 KB each)
//                  bufQ[2] @ 73728 + {0,16384}  ([qt8][hl2][lane64][16B])
//                  sP (128x576 f16, row pitch 1152B, 16B-unit XOR swizzle) aliases @ 0..147456
__global__ __launch_bounds__(1024)
void fusion_main(const float* __restrict__ Q, const unsigned short* __restrict__ Kf,
                 const unsigned short* __restrict__ Vf, float* __restrict__ Out)
{
  __shared__ alignas(16) unsigned char lds[147456];
  __shared__ float sRa[4][128];
  __shared__ float sRb[4][128];

  const int tid  = threadIdx.x;
  const int lane = tid & 63;
  const int w    = tid >> 6;      // 0..15
  const int g    = lane >> 4;
  const int ln   = lane & 15;
  const int wq   = w >> 2;        // QK: 0..3, q rows [wq*32,+32)
  const int wkv  = w & 3;         // QK: kv slice [wkv*144,+144)
  const int wq2  = w >> 3;        // PV: 0..1
  const int wd8  = w & 7;         // PV: d slice [wd8*96,+96)

  // XCD swizzle: all 8 q-blocks of a batch on one XCD
  const int bid = blockIdx.x;
  const int xcd = bid & 7, ii = bid >> 3;
  const int b  = (xcd << 2) | (ii >> 3);
  const int q0 = (ii & 7) * 128;

  const float* Qb = Q + ((size_t)(b * Nn + q0)) * Dd;
  const unsigned char* KfB = (const unsigned char*)Kf + ((size_t)(b * 36 * 24) << 10);
  const unsigned short* VfB = Vf + ((size_t)(b * 18 * 48) << 9);

  // Q staging constants: wave-uniform qtile/half, per-lane row/col
  const int qt_s = w >> 1;        // 0..7
  const int jh_s = w & 1;         // 0..1
  const float* qsrc = Qb + (size_t)(qt_s * 16 + ln) * Dd + g * 8 + jh_s * 4;
  unsigned char* qdst = lds + 73728 + qt_s * 2048 + lane * 16 + jh_s * 8;

  // ---------------- prologue: stage chunk 0 into buf 0
  {
#pragma unroll
    for (int nt = w; nt < 36; nt += 16)
      gll16(KfB + ((size_t)(nt * 24) << 10) + (lane << 4), lds + nt * 1024);
    f32x4 qv = *(const f32x4*)qsrc;
    us4 hv, lv;
#pragma unroll
    for (int k = 0; k < 4; ++k) {
      float x = qv[k] * L2E;
      _Float16 hh = (_Float16)x;
      hv[k] = __builtin_bit_cast(unsigned short, hh);
      lv[k] = __builtin_bit_cast(unsigned short, (_Float16)(x - (float)hh));
    }
    *(us4*)qdst = hv;
    *(us4*)(qdst + 1024) = lv;
    __syncthreads();
  }

  // ---------------- QK: acc[mt 2][nt 9] = [32 q][144 kv]
  f32x4 acc[2][9];
#pragma unroll
  for (int mt = 0; mt < 2; ++mt)
#pragma unroll
    for (int nt = 0; nt < 9; ++nt) acc[mt][nt] = (f32x4){0.f, 0.f, 0.f, 0.f};

#pragma unroll 1
  for (int c = 0; c < 24; ++c) {
    const int cur = c & 1, nxt = cur ^ 1;
    const bool stg = (c < 23);
    f32x4 qv;
    if (stg) {  // issue next-chunk K gll16 + Q loads early
#pragma unroll
      for (int nt = w; nt < 36; nt += 16)
        gll16(KfB + ((size_t)(nt * 24 + c + 1) << 10) + (lane << 4),
              lds + nxt * 36864 + nt * 1024);
      qv = *(const f32x4*)(qsrc + (c + 1) * 32);
    }
    // compute on cur
    const unsigned char* qb = lds + 73728 + cur * 16384;
    h8 qh[2], ql[2];
#pragma unroll
    for (int mt = 0; mt < 2; ++mt) {
      qh[mt] = *(const h8*)(qb + (wq * 2 + mt) * 2048 + lane * 16);
      ql[mt] = *(const h8*)(qb + (wq * 2 + mt) * 2048 + 1024 + lane * 16);
    }
    const unsigned char* kb = lds + cur * 36864;
#pragma unroll
    for (int nt = 0; nt < 9; ++nt) {
      const h8 kf = *(const h8*)(kb + (wkv * 9 + nt) * 1024 + lane * 16);
#pragma unroll
      for (int mt = 0; mt < 2; ++mt) {
        acc[mt][nt] = __builtin_amdgcn_mfma_f32_16x16x32_f16(qh[mt], kf, acc[mt][nt], 0, 0, 0);
        acc[mt][nt] = __builtin_amdgcn_mfma_f32_16x16x32_f16(ql[mt], kf, acc[mt][nt], 0, 0, 0);
      }
    }
    if (stg) {  // convert + write Q late (loads landed under MFMA)
      us4 hv, lv;
#pragma unroll
      for (int k = 0; k < 4; ++k) {
        float x = qv[k] * L2E;
        _Float16 hh = (_Float16)x;
        hv[k] = __builtin_bit_cast(unsigned short, hh);
        lv[k] = __builtin_bit_cast(unsigned short, (_Float16)(x - (float)hh));
      }
      *(us4*)(qdst + nxt * 16384) = hv;
      *(us4*)(qdst + nxt * 16384 + 1024) = lv;
    }
    __syncthreads();
  }

  // ---------------- one-shot softmax (exp2 domain)
  float pm[2][4];
#pragma unroll
  for (int mt = 0; mt < 2; ++mt)
#pragma unroll
    for (int i2 = 0; i2 < 4; ++i2) {
      float v = acc[mt][0][i2];
#pragma unroll
      for (int nt = 1; nt < 9; ++nt) v = fmaxf(v, acc[mt][nt][i2]);
      pm[mt][i2] = v;
    }
#pragma unroll
  for (int mk = 1; mk < 16; mk <<= 1)
#pragma unroll
    for (int mt = 0; mt < 2; ++mt)
#pragma unroll
      for (int i2 = 0; i2 < 4; ++i2)
        pm[mt][i2] = fmaxf(pm[mt][i2], __shfl_xor(pm[mt][i2], mk, 64));
  if (ln == 0) {
#pragma unroll
    for (int mt = 0; mt < 2; ++mt)
#pragma unroll
      for (int i2 = 0; i2 < 4; ++i2)
        sRa[wkv][wq * 32 + mt * 16 + g * 4 + i2] = pm[mt][i2];
  }
  __syncthreads();

  float mfin[2][4], ps[2][4];
#pragma unroll
  for (int mt = 0; mt < 2; ++mt)
#pragma unroll
    for (int i2 = 0; i2 < 4; ++i2) {
      const int rw = wq * 32 + mt * 16 + g * 4 + i2;
      mfin[mt][i2] = fmaxf(fmaxf(sRa[0][rw], sRa[1][rw]), fmaxf(sRa[2][rw], sRa[3][rw]));
      ps[mt][i2] = 0.f;
    }
#pragma unroll
  for (int mt = 0; mt < 2; ++mt)
#pragma unroll
    for (int nt = 0; nt < 9; ++nt)
#pragma unroll
      for (int i2 = 0; i2 < 4; ++i2) {
        const float p = exp2f(acc[mt][nt][i2] - mfin[mt][i2]);
        acc[mt][nt][i2] = p;
        ps[mt][i2] += p;
      }
#pragma unroll
  for (int mk = 1; mk < 16; mk <<= 1)
#pragma unroll
    for (int mt = 0; mt < 2; ++mt)
#pragma unroll
      for (int i2 = 0; i2 < 4; ++i2)
        ps[mt][i2] += __shfl_xor(ps[mt][i2], mk, 64);
  if (ln == 0) {
#pragma unroll
    for (int mt = 0; mt < 2; ++mt)
#pragma unroll
      for (int i2 = 0; i2 < 4; ++i2)
        sRb[wkv][wq * 32 + mt * 16 + g * 4 + i2] = ps[mt][i2];
  }
  __syncthreads();

  // normalize P, write to swizzled sP (aliases dead K/Q buffers)
  {
    unsigned short* sPp = (unsigned short*)lds;
#pragma unroll
    for (int mt = 0; mt < 2; ++mt)
#pragma unroll
      for (int i2 = 0; i2 < 4; ++i2) {
        const int rw = wq * 32 + mt * 16 + g * 4 + i2;
        const float inv = 1.0f / ((sRb[0][rw] + sRb[1][rw]) + (sRb[2][rw] + sRb[3][rw]));
#pragma unroll
        for (int nt = 0; nt < 9; ++nt) {
          const int u = wkv * 18 + nt * 2 + (ln >> 3);
          sPp[rw * 576 + ((u ^ (rw & 7)) << 3) + (ln & 7)] = f2h(acc[mt][nt][i2] * inv);
        }
      }
  }
  __syncthreads();

  // ---------------- PV: two passes of 32q x 96d per wave; V frags direct from global
#pragma unroll 1
  for (int p = 0; p < 2; ++p) {
    const int qr0 = (wq2 * 2 + p) * 32;
    f32x4 O[2][6];
#pragma unroll
    for (int mt = 0; mt < 2; ++mt)
#pragma unroll
      for (int nt = 0; nt < 6; ++nt) O[mt][nt] = (f32x4){0.f, 0.f, 0.f, 0.f};

#pragma unroll 1
    for (int kc = 0; kc < 18; ++kc) {
      h8 pa[2];
#pragma unroll
      for (int mt = 0; mt < 2; ++mt) {
        const int row = qr0 + mt * 16 + ln;
        const int u = kc * 4 + g;
        pa[mt] = *(const h8*)(lds + row * 1152 + ((u ^ (row & 7)) << 4));
      }
      const unsigned short* vb = VfB + ((size_t)(kc * 48 + wd8 * 6) << 9) + lane * 8;
#pragma unroll
      for (int nt = 0; nt < 6; ++nt) {
        const h8 vf = *(const h8*)(vb + ((size_t)nt << 9));
#pragma unroll
        for (int mt = 0; mt < 2; ++mt)
          O[mt][nt] = __builtin_amdgcn_mfma_f32_16x16x32_f16(pa[mt], vf, O[mt][nt], 0, 0, 0);
      }
    }
    float* ob = Out + ((size_t)(b * Nn + q0 + qr0)) * Dd;
#pragma unroll
    for (int mt = 0; mt < 2; ++mt)
#pragma unroll
      for (int nt = 0; nt < 6; ++nt)
#pragma unroll
        for (int i2 = 0; i2 < 4; ++i2)
          ob[(size_t)(mt * 16 + g * 4 + i2) * Dd + wd8 * 96 + nt * 16 + ln] = O[mt][nt][i2];
  }
}

extern "C" void kernel_launch(void* const* d_in, const int* in_sizes, int n_in,
                              void* d_out, int out_size, void* d_ws, size_t ws_size,
                              hipStream_t stream) {
  const float* Q = (const float*)d_in[0];
  const float* K = (const float*)d_in[1];
  float* Out = (float*)d_out;
  unsigned short* Kf = (unsigned short*)d_ws;
  unsigned short* Vf = Kf + KF_ELEMS;
  fusion_prep<<<dim3(Bb * 24), dim3(256), 0, stream>>>(K, Kf, Vf);
  fusion_main<<<dim3(Bb * 8), dim3(1024), 0, stream>>>(Q, Kf, Vf, Out);
}